// Round 2
// baseline (169.452 us; speedup 1.0000x reference)
//
#include <hip/hip_runtime.h>
#include <hip/hip_fp16.h>
#include <cstdint>

// ---------------------------------------------------------------------------
// SingleDeformConv on MI355X (gfx950)
// data (8,64,128,128) f32; w (64,64,3,3); b (64); w_off (18,64,3,3); b_off(18);
// w_mod (9,64,3,3); b_mod (9).  out = relu(deform_conv(...)) (8,64,128,128) f32
//
// R12 -> R13: FUSE conv27 into deform_main. rocprof showed deform_main at
// 45 us is only 28% of the 162 us total -- prep_k + conv27_k + launch gaps
// are ~117 us. Each deform block (64 pos = half a row) now computes its own
// 27-channel offset/mask conv from a 3x66 halo tile of dataT (L2/L3-hot),
// writes the 27 values to an LDS scratch pp[64][28], and the params phase
// reads pp instead of the offP HBM buffer. Removes: conv27_k launch, its
// 39 MB staging pass, and the 28 MB offP HBM round-trip. LDS regions are
// time-multiplexed (tile27/pp die before pOff/pW/samp go live): 35680 B.
// Tap pipeline below is byte-identical to R12 (clean attribution).
// ---------------------------------------------------------------------------

typedef _Float16 half8 __attribute__((ext_vector_type(8)));
typedef __attribute__((ext_vector_type(4))) float floatx4;

// pack two floats -> f16x2 dword (RNE)
__device__ __forceinline__ unsigned int pack2h(float lo, float hi) {
    __half2 h = __floats2half2_rn(lo, hi);
    union { __half2 h; unsigned int u; } cv; cv.h = h;
    return cv.u;
}
// blend one f16x2 dword from 4 corners with broadcast __half2 weights
__device__ __forceinline__ unsigned int blend2h(unsigned int a, unsigned int b,
                                                unsigned int c, unsigned int d,
                                                const __half2* w) {
    union { unsigned int u; __half2 h; } A, B, C, D, O;
    A.u = a; B.u = b; C.u = c; D.u = d;
    __half2 s = __hmul2(A.h, w[0]);
    s = __hfma2(B.h, w[1], s);
    s = __hfma2(C.h, w[2], s);
    s = __hfma2(D.h, w[3], s);
    O.h = s;
    return O.u;
}

// Workspace layout (bytes)
#define OFF_DATAT 0u               // [8][16384][64] f16   = 16777216 B
#define OFF_WM    16777216u        // [64][576] f16        = 73728 B
#define OFF_W27   16850944u        // [32][576] f16        = 36864 B
#define OFF_B27   16887808u        // [32] f32             = 128 B
// total 16887936 B

// ---------------------------------------------------------------------------
// Kernel 1: prep = NCHW f32 -> NHWC f16 transpose (blocks 0..2047)
//           + weight packing / bias27 (blocks 2048..2263)
// ---------------------------------------------------------------------------
__global__ __launch_bounds__(256) void prep_k(const float* __restrict__ x,
                                              unsigned short* __restrict__ xt,
                                              const float* __restrict__ w,
                                              const float* __restrict__ w_off,
                                              const float* __restrict__ w_mod,
                                              const float* __restrict__ b_off,
                                              const float* __restrict__ b_mod,
                                              unsigned short* __restrict__ wpackM,
                                              unsigned short* __restrict__ wpack27,
                                              float* __restrict__ bias27) {
    __shared__ float tile[64][65];
    int blk = blockIdx.x;
    if (blk < 2048) {                              // ---- transpose ----
        int b    = blk >> 8;
        int pos0 = (blk & 255) << 6;
        int lane = threadIdx.x & 63;
        int g    = threadIdx.x >> 6;
        for (int c = g; c < 64; c += 4)
            tile[c][lane] = x[(((b << 6) + c) << 14) + pos0 + lane];
        __syncthreads();
        int c2 = lane & 31;
        for (int i = g; i < 32; i += 4) {
            int pr = (i << 1) + (lane >> 5);
            unsigned int d = pack2h(tile[c2 << 1][pr], tile[(c2 << 1) + 1][pr]);
            *(unsigned int*)&xt[((size_t)((b << 14) + pos0 + pr) << 6) + (c2 << 1)] = d;
        }
        return;
    }
    // ---- weight packing ----
    int t = (blk - 2048) * 256 + threadIdx.x;
    if (t < 64 * 576) {
        int o = t / 576, kk = t % 576;
        int k = kk >> 6, c = kk & 63;
        wpackM[t] = __half_as_ushort(__float2half_rn(w[(o * 64 + c) * 9 + k]));
        return;
    }
    t -= 64 * 576;
    if (t < 32 * 576) {
        int o = t / 576, kk = t % 576;
        int k = kk >> 6, c = kk & 63;
        float v = 0.f;
        if (o < 18)      v = w_off[(o * 64 + c) * 9 + k];
        else if (o < 27) v = w_mod[((o - 18) * 64 + c) * 9 + k];
        wpack27[t] = __half_as_ushort(__float2half_rn(v));
        if (kk == 0) bias27[o] = (o < 18) ? b_off[o] : (o < 27 ? b_mod[o - 18] : 0.f);
    }
}

// ---------------------------------------------------------------------------
// Kernel 2 (fused): 27-ch offset/mask conv (in-block) + main deformable conv.
//
// LDS time-multiplexing (35680 B total):
//   phase A: tile27 [3][66][72] f16 @0     (28512 B)   halo stage + conv27
//            pp     [64][28]   f32 @28512  ( 7168 B)   27-ch results
//   phase B: pOff   [576] u16x4   @0       ( 4608 B)   } written AFTER tile27
//            pW     [576] u32x4   @4608    ( 9216 B)   } dead (post-barrier)
//            samp [2][64][72] f16 @13824   (18432 B)   written after pp dead
// ---------------------------------------------------------------------------
__global__ __launch_bounds__(256, 3) void deform_main_k(const unsigned short* __restrict__ xt,
                                                        const unsigned short* __restrict__ wpackM,
                                                        const unsigned short* __restrict__ wpack27,
                                                        const float* __restrict__ bias27,
                                                        const float* __restrict__ bias,
                                                        float* __restrict__ out) {
    __shared__ __align__(16) char ldsbuf[35680];
    ushort4*        pOff   = (ushort4*)(ldsbuf);                                  // [576]
    uint4*          pW     = (uint4*)(ldsbuf + 4608);                             // [576]
    unsigned short (*samp)[64][72]   = (unsigned short (*)[64][72])(ldsbuf + 13824); // [2][64][72]
    unsigned short (*tile27)[66][72] = (unsigned short (*)[66][72])(ldsbuf);      // [3][66][72]
    float          (*pp)[28]         = (float (*)[28])(ldsbuf + 28512);           // [64][28]

    int blk  = blockIdx.x;                          // 2048 = 8 b * 256
    int b    = blk >> 8;
    int pos0 = (blk & 255) << 6;
    int tid  = threadIdx.x;
    int lane = tid & 63, wv = tid >> 6;
    int r = lane & 15, q = lane >> 4;
    int pg = lane >> 3;                             // position subgroup 0..7
    int j8 = lane & 7;                              // channel chunk (8 f16 = 16B)

    const unsigned short* xb = xt + ((size_t)b << 20);
    const char* xbb = (const char*)xb;

    // ================= phase A: in-block conv27 =================
    {
        int row = pos0 >> 7;                        // output row (one per block)
        int c0  = pos0 & 127;                       // 0 or 64
        // stage 3x66 halo positions x 64ch f16 (zero-padded at borders)
        for (int e = tid; e < 1584; e += 256) {     // 1584 = 3*66*8 uint4 chunks
            int rr  = e / 528;                      // 528 = 66*8
            int rem = e - rr * 528;
            int cc  = rem >> 3;
            int j   = rem & 7;
            int sy  = row - 1 + rr;
            int sx  = c0 - 1 + cc;
            uint4 v = {0u, 0u, 0u, 0u};
            if (sy >= 0 && sy < 128 && sx >= 0 && sx < 128)
                v = *(const uint4*)&xb[(size_t)(((sy << 7) + sx) << 6) + (j << 3)];
            *(uint4*)&tile27[rr][cc][j << 3] = v;
        }
        __syncthreads();

        // implicit GEMM: 32(padded-27) oc x 16 pos (wave wv owns pos tile wv)
        floatx4 acc27[2] = {};
        #pragma unroll
        for (int k = 0; k < 9; ++k) {
            int ki = k / 3, kj = k % 3;
            #pragma unroll
            for (int chh = 0; chh < 2; ++chh) {
                half8 a0 = *(const half8*)&wpack27[(r)      * 576 + (k << 6) + (chh << 5) + (q << 3)];
                half8 a1 = *(const half8*)&wpack27[(16 + r) * 576 + (k << 6) + (chh << 5) + (q << 3)];
                half8 bf = *(const half8*)&tile27[ki][(wv << 4) + r + kj][(chh << 5) + (q << 3)];
                acc27[0] = __builtin_amdgcn_mfma_f32_16x16x32_f16(a0, bf, acc27[0], 0, 0, 0);
                acc27[1] = __builtin_amdgcn_mfma_f32_16x16x32_f16(a1, bf, acc27[1], 0, 0, 0);
            }
        }
        // bias + sigmoid(mask) -> pp[pos][oc]  (C/D layout: col=r, row=q*4+reg)
        #pragma unroll
        for (int s = 0; s < 2; ++s) {
            #pragma unroll
            for (int reg = 0; reg < 4; ++reg) {
                int oc = (s << 4) + (q << 2) + reg;
                if (oc < 27) {
                    float v = acc27[s][reg] + bias27[oc];
                    if (oc >= 18) v = 2.f / (1.f + __expf(-v));
                    pp[(wv << 4) + r][oc] = v;
                }
            }
        }
        __syncthreads();    // pp visible; all tile27 reads done (pOff/pW region free)
    }

    // ================= params phase (reads pp, writes pOff/pW) =================
    for (int e = tid; e < 576; e += 256) {
        int k = e >> 6, p = e & 63;
        int pos = pos0 + p;
        float dy = pp[p][(k << 1)];
        float dx = pp[p][(k << 1) + 1];
        float m  = pp[p][18 + k];
        float py = (float)(pos >> 7) + (float)(k / 3 - 1) + dy;
        float px = (float)(pos & 127) + (float)(k % 3 - 1) + dx;
        float y0f = floorf(py), x0f = floorf(px);
        int y0 = (int)y0f, x0 = (int)x0f;
        float wy1 = py - y0f, wx1 = px - x0f;
        float wy0 = 1.f - wy1, wx0 = 1.f - wx1;
        bool vy0 = (y0 >= 0) && (y0 < 128);
        bool vy1 = (y0 >= -1) && (y0 < 127);
        bool vx0 = (x0 >= 0) && (x0 < 128);
        bool vx1 = (x0 >= -1) && (x0 < 127);
        float w00 = (vy0 && vx0) ? m * wy0 * wx0 : 0.f;
        float w01 = (vy0 && vx1) ? m * wy0 * wx1 : 0.f;
        float w10 = (vy1 && vx0) ? m * wy1 * wx0 : 0.f;
        float w11 = (vy1 && vx1) ? m * wy1 * wx1 : 0.f;
        int y0c = min(max(y0, 0), 127), y1c = min(max(y0 + 1, 0), 127);
        int x0c = min(max(x0, 0), 127), x1c = min(max(x0 + 1, 0), 127);
        ushort4 io;
        io.x = (unsigned short)((y0c << 7) + x0c);
        io.y = (unsigned short)((y0c << 7) + x1c);
        io.z = (unsigned short)((y1c << 7) + x0c);
        io.w = (unsigned short)((y1c << 7) + x1c);
        pOff[e] = io;
        union { uint4 u; __half2 h[4]; } pw;
        pw.h[0] = __float2half2_rn(w00);
        pw.h[1] = __float2half2_rn(w01);
        pw.h[2] = __float2half2_rn(w10);
        pw.h[3] = __float2half2_rn(w11);
        pW[e] = pw.u;
    }
    __syncthreads();                                // pOff/pW ready; pp dead

    // ================= tap pipeline (identical to R12) =================
    floatx4 acc[4] = {};
    const char* xp = xbb + (j8 << 4);               // per-lane channel-chunk base
    const unsigned short* wrow = wpackM + ((wv << 4) + r) * 576 + (q << 3);

    uint4   c00[2][2], c01[2][2], c10[2][2], c11[2][2];  // [set][i]
    uint4   cwS[2][2];                              // weights per set
    ushort4 nio[2];                                 // staged params (next issue)
    uint4   ncw[2];
    half8   afC[2], afN[2];                         // A-frags, current / next

    auto readParams = [&](int k) {
        #pragma unroll
        for (int i = 0; i < 2; ++i) {
            int e  = (k << 6) + (wv << 4) + (i << 3) + pg;
            nio[i] = pOff[e];
            ncw[i] = pW[e];
        }
    };
    auto issueInto = [&](int s) {                   // s is compile-time at all call sites
        #pragma unroll
        for (int i = 0; i < 2; ++i) {
            cwS[s][i] = ncw[i];
            c00[s][i] = *(const uint4*)(xp + ((int)nio[i].x << 7));
            c01[s][i] = *(const uint4*)(xp + ((int)nio[i].y << 7));
            c10[s][i] = *(const uint4*)(xp + ((int)nio[i].z << 7));
            c11[s][i] = *(const uint4*)(xp + ((int)nio[i].w << 7));
        }
    };
    auto blendStore = [&](int s, int buf) {         // s, buf compile-time
        #pragma unroll
        for (int i = 0; i < 2; ++i) {
            int p = (wv << 4) + (i << 3) + pg;
            union { uint4 u; __half2 h[4]; } W; W.u = cwS[s][i];
            uint4 o4;
            o4.x = blend2h(c00[s][i].x, c01[s][i].x, c10[s][i].x, c11[s][i].x, W.h);
            o4.y = blend2h(c00[s][i].y, c01[s][i].y, c10[s][i].y, c11[s][i].y, W.h);
            o4.z = blend2h(c00[s][i].z, c01[s][i].z, c10[s][i].z, c11[s][i].z, W.h);
            o4.w = blend2h(c00[s][i].w, c01[s][i].w, c10[s][i].w, c11[s][i].w, W.h);
            *(uint4*)&samp[buf][p][j8 << 3] = o4;
        }
    };

    // LDS-only barrier: commit this wave's ds_writes (lgkmcnt), then barrier.
    // Does NOT drain vmcnt — in-flight corner gathers survive the barrier.
    auto ldsBarrier = [&]() {
        asm volatile("s_waitcnt lgkmcnt(0)\n\ts_barrier" ::: "memory");
    };

    // prologue: taps 0 and 1 into the pipe; params(2) staged
    readParams(0); issueInto(0);
    readParams(1); issueInto(1);
    afC[0] = *(const half8*)&wrow[0];
    afC[1] = *(const half8*)&wrow[32];
    blendStore(0, 0);                               // blend tap0 -> samp[0]
    readParams(2);

    #pragma unroll
    for (int k = 0; k < 9; ++k) {
        if (k <= 6) issueInto(k & 1);               // corners for tap k+2
        if (k < 8) {
            afN[0] = *(const half8*)&wrow[((k + 1) << 6)];
            afN[1] = *(const half8*)&wrow[((k + 1) << 6) + 32];
        }
        ldsBarrier();                               // samp[k&1] complete block-wide
        #pragma unroll
        for (int ch = 0; ch < 2; ++ch) {
            #pragma unroll
            for (int nt = 0; nt < 4; ++nt) {
                half8 bfrag = *(const half8*)&samp[k & 1][(nt << 4) + r][(ch << 5) + (q << 3)];
                acc[nt] = __builtin_amdgcn_mfma_f32_16x16x32_f16(afC[ch], bfrag, acc[nt], 0, 0, 0);
            }
        }
        if (k < 8) {
            blendStore((k + 1) & 1, (k + 1) & 1);   // corners issued at body k-1
            if (k <= 5) readParams(k + 3);          // params for issue at body k+1
            afC[0] = afN[0];
            afC[1] = afN[1];
        }
    }

    #pragma unroll
    for (int nt = 0; nt < 4; ++nt) {
        #pragma unroll
        for (int reg = 0; reg < 4; ++reg) {
            int oc  = (wv << 4) + (q << 2) + reg;
            int pos = pos0 + (nt << 4) + r;
            float v = acc[nt][reg] + bias[oc];
            out[(size_t)(((b << 6) + oc) << 14) + pos] = fmaxf(v, 0.f);
        }
    }
}

// ---------------------------------------------------------------------------
extern "C" void kernel_launch(void* const* d_in, const int* in_sizes, int n_in,
                              void* d_out, int out_size, void* d_ws, size_t ws_size,
                              hipStream_t stream) {
    const float* data  = (const float*)d_in[0];
    const float* w     = (const float*)d_in[1];
    const float* bias  = (const float*)d_in[2];
    const float* w_off = (const float*)d_in[3];
    const float* b_off = (const float*)d_in[4];
    const float* w_mod = (const float*)d_in[5];
    const float* b_mod = (const float*)d_in[6];
    float* out = (float*)d_out;

    char* ws = (char*)d_ws;
    unsigned short* dataT   = (unsigned short*)(ws + OFF_DATAT);
    unsigned short* wpackM  = (unsigned short*)(ws + OFF_WM);
    unsigned short* wpack27 = (unsigned short*)(ws + OFF_W27);
    float*          bias27  = (float*)(ws + OFF_B27);

    prep_k<<<2264, 256, 0, stream>>>(data, dataT, w, w_off, w_mod,
                                     b_off, b_mod, wpackM, wpack27, bias27);
    deform_main_k<<<2048, 256, 0, stream>>>(dataT, wpackM, wpack27, bias27, bias, out);
}